// Round 2
// 867.422 us; speedup vs baseline: 1.0339x; 1.0339x over previous
//
#include <hip/hip_runtime.h>

typedef unsigned short u16;
typedef __attribute__((ext_vector_type(8))) __bf16 bf16x8;
typedef __attribute__((ext_vector_type(4))) float f32x4;
typedef __attribute__((ext_vector_type(16))) float f32x16;

__device__ __forceinline__ u16 f2bf(float x) {
    union { float f; unsigned int u; } v; v.f = x;
    unsigned int r = v.u + 0x7fffu + ((v.u >> 16) & 1u);
    return (u16)(r >> 16);
}

// direct global->LDS async copy, 16B per lane. LDS dest must be wave-uniform;
// HW writes base + lane*16.
typedef const __attribute__((address_space(1))) void* gas_ptr;
typedef __attribute__((address_space(3))) void* las_ptr;
#define GLOAD_LDS16(g, l) __builtin_amdgcn_global_load_lds((gas_ptr)(const void*)(g), (las_ptr)(void*)(l), 16, 0, 0)

// ---------------- fp32 -> bf16 conversion (8 elems/thread) ----------------
__global__ void cvt_bf16(const float* __restrict__ src, u16* __restrict__ dst, int n8) {
    int i = blockIdx.x * blockDim.x + threadIdx.x;
    if (i >= n8) return;
    const float4* s = (const float4*)src + (size_t)i * 2;
    float4 a = s[0], b = s[1];
    union { u16 u[8]; uint4 v; } o;
    o.u[0] = f2bf(a.x); o.u[1] = f2bf(a.y); o.u[2] = f2bf(a.z); o.u[3] = f2bf(a.w);
    o.u[4] = f2bf(b.x); o.u[5] = f2bf(b.y); o.u[6] = f2bf(b.z); o.u[7] = f2bf(b.w);
    *((uint4*)dst + i) = o.v;
}

// ---------------- QKV projection GEMM: Y[M][3072] = X[M][1024] @ Wcat^T + bias --------
// 128x128 tile, BK=32, 4 waves of 64x64, 16x16x32 bf16 MFMA.
// Staging: global_load_lds width=16 (m97 structure). LDS layout is chunk-linear in
// tid order (chunk c = (kg=c>>7, row=c&127) at u16 offset kg*1024 + row*8), which is
// exactly the wave-uniform-base + lane*16B pattern the HW requires.
__global__ __launch_bounds__(256) void gemm_qkv(
    const u16* __restrict__ X, const u16* __restrict__ W,
    const float* __restrict__ bQ, const float* __restrict__ bK,
    const float* __restrict__ bV, u16* __restrict__ Y)
{
    __shared__ __align__(16) u16 As[4096];
    __shared__ __align__(16) u16 Bs[4096];
    const int tid = threadIdx.x;
    const int w = tid >> 6, lane = tid & 63;
    const int wm = (w >> 1) << 6, wn = (w & 1) << 6;
    const size_t mBase = (size_t)blockIdx.y << 7;
    const int nBase = blockIdx.x << 7;
    const int l15 = lane & 15, kq = lane >> 4;

    // per-lane global sources: thread tid covers chunk tid (kg = tid>>7) and chunk 256+tid (kg+2)
    const int rA = tid & 127;
    const int gA = tid >> 7;
    const u16* xs0 = X + (mBase + rA) * 1024 + gA * 8;
    const u16* xs1 = xs0 + 16;   // kg+2
    const u16* ws0 = W + (size_t)(nBase + rA) * 1024 + gA * 8;
    const u16* ws1 = ws0 + 16;

    // wave-uniform LDS bases: wave w's first issue covers chunks [w*64, w*64+64),
    // second issue covers [256+w*64, ...). chunk = 8 u16 = 16B.
    u16* lA0 = As + w * 512;
    u16* lA1 = As + 2048 + w * 512;
    u16* lB0 = Bs + w * 512;
    u16* lB1 = Bs + 2048 + w * 512;

    f32x4 acc[4][4];
    for (int mi = 0; mi < 4; ++mi)
        for (int ni = 0; ni < 4; ++ni)
            for (int r = 0; r < 4; ++r) acc[mi][ni][r] = 0.f;

    for (int k0 = 0; k0 < 1024; k0 += 32) {
        __syncthreads();                      // all waves done reading previous tile
        GLOAD_LDS16(xs0 + k0, lA0);
        GLOAD_LDS16(xs1 + k0, lA1);
        GLOAD_LDS16(ws0 + k0, lB0);
        GLOAD_LDS16(ws1 + k0, lB1);
        __syncthreads();                      // compiler drains vmcnt(0): tile visible
        bf16x8 af[4], bfr[4];
#pragma unroll
        for (int mi = 0; mi < 4; ++mi)
            af[mi] = *(const bf16x8*)&As[kq * 1024 + (wm + mi * 16 + l15) * 8];
#pragma unroll
        for (int ni = 0; ni < 4; ++ni)
            bfr[ni] = *(const bf16x8*)&Bs[kq * 1024 + (wn + ni * 16 + l15) * 8];
#pragma unroll
        for (int mi = 0; mi < 4; ++mi)
#pragma unroll
            for (int ni = 0; ni < 4; ++ni)
                acc[mi][ni] = __builtin_amdgcn_mfma_f32_16x16x32_bf16(af[mi], bfr[ni], acc[mi][ni], 0, 0, 0);
    }

    const int third = nBase >> 10;
    const float* bias = (third == 0) ? bQ : ((third == 1) ? bK : bV);
    const int bcol = (nBase & 1023) + wn + l15;
    float bv[4];
#pragma unroll
    for (int ni = 0; ni < 4; ++ni) bv[ni] = bias[bcol + ni * 16];
#pragma unroll
    for (int mi = 0; mi < 4; ++mi) {
        size_t rb = mBase + wm + mi * 16 + kq * 4;
#pragma unroll
        for (int ni = 0; ni < 4; ++ni) {
            int col = nBase + wn + ni * 16 + l15;
#pragma unroll
            for (int r = 0; r < 4; ++r)
                Y[(rb + r) * 3072 + col] = f2bf(acc[mi][ni][r] + bv[ni]);
        }
    }
}

// ---------------- fused decay attention: one wave per (batch, head) ----------------
// scores = exp(q k^T / 8) masked by j<len; coef = scores/rowsum + Md; out = coef @ v.
__global__ __launch_bounds__(256) void attn_dec(
    const u16* __restrict__ Y, const int* __restrict__ lenp, float* __restrict__ out)
{
    __shared__ __align__(16) u16 coefLds[4][1024];   // [32][32] bf16 per wave
    __shared__ __align__(16) u16 vLds[4][1280];      // [20][64] bf16 per wave
    const int tid = threadIdx.x;
    const int w = tid >> 6, lane = tid & 63;
    const int u = blockIdx.x * 4 + w;
    const int b = u >> 4, h = u & 15;
    const int L = lenp[b];
    const int j32 = lane & 31, hw = lane >> 5;
    const int m19 = (j32 < 19) ? j32 : 19;

    const u16* qb = Y + (size_t)b * 61440 + h * 64;
    const u16* kb = qb + 1024;
    const u16* vb = qb + 2048;

    // QK^T : rows m = lane&31 (clamped), K over d=0..63 in 4 MFMAs
    f32x16 s;
    for (int r = 0; r < 16; ++r) s[r] = 0.f;
#pragma unroll
    for (int kc = 0; kc < 4; ++kc) {
        const int off = kc * 16 + hw * 8;
        bf16x8 aq = *(const bf16x8*)(qb + (size_t)m19 * 3072 + off);
        bf16x8 bk = *(const bf16x8*)(kb + (size_t)m19 * 3072 + off);
        s = __builtin_amdgcn_mfma_f32_32x32x16_bf16(aq, bk, s, 0, 0, 0);
    }

    // stage v[20][64] into LDS (16B chunks)
#pragma unroll
    for (int t = 0; t < 3; ++t) {
        int c = t * 64 + lane;
        if (c < 160) {
            uint4 d = *(const uint4*)(vb + (size_t)(c >> 3) * 3072 + (c & 7) * 8);
            *(uint4*)&vLds[w][c * 8] = d;
        }
    }

    // exp, mask, rowsum (32-lane butterfly), coef = attn + Md, store to LDS in A-layout
#pragma unroll
    for (int r = 0; r < 16; ++r) {
        int i = (r & 3) + ((r >> 2) << 3) + (hw << 2);
        float ev = (i < 20 && j32 < L) ? __expf(s[r] * 0.125f) : 0.f;
        float sum = ev;
#pragma unroll
        for (int o = 1; o < 32; o <<= 1) sum += __shfl_xor(sum, o, 32);
        float coef = ev / (sum + 1e-8f);
        if (i < 20 && j32 < 20) coef -= (float)((i > j32) ? (i - j32) : (j32 - i));
        if (i >= 20 || j32 >= 20) coef = 0.f;
        coefLds[w][i * 32 + j32] = f2bf(coef);
    }
    __syncthreads();

    // PV: D[i][d] = sum_j coef[i][j] v[j][d] ; N=64 as two 32-col tiles, K=32
    f32x16 o0, o1;
    for (int r = 0; r < 16; ++r) { o0[r] = 0.f; o1[r] = 0.f; }
#pragma unroll
    for (int kc = 0; kc < 2; ++kc) {
        bf16x8 ac = *(const bf16x8*)&coefLds[w][j32 * 32 + kc * 16 + hw * 8];
        bf16x8 bv0, bv1;
#pragma unroll
        for (int jj = 0; jj < 8; ++jj) {
            int j = kc * 16 + hw * 8 + jj;
            int jc = (j < 19) ? j : 19;     // coef=0 for j>=20; value irrelevant, stay in-bounds
            bv0[jj] = *(const __bf16*)&vLds[w][jc * 64 + j32];
            bv1[jj] = *(const __bf16*)&vLds[w][jc * 64 + 32 + j32];
        }
        o0 = __builtin_amdgcn_mfma_f32_32x32x16_bf16(ac, bv0, o0, 0, 0, 0);
        o1 = __builtin_amdgcn_mfma_f32_32x32x16_bf16(ac, bv1, o1, 0, 0, 0);
    }

#pragma unroll
    for (int r = 0; r < 16; ++r) {
        int i = (r & 3) + ((r >> 2) << 3) + (hw << 2);
        if (i < 20) {
            size_t ro = ((size_t)b * 20 + i) * 1024 + h * 64 + j32;
            out[ro] = o0[r];
            out[ro + 32] = o1[r];
        }
    }
}

// ---------------- driver ----------------
extern "C" void kernel_launch(void* const* d_in, const int* in_sizes, int n_in,
                              void* d_out, int out_size, void* d_ws, size_t ws_size,
                              hipStream_t stream) {
    const float* Q   = (const float*)d_in[0];
    const float* W_Q = (const float*)d_in[1];
    const float* b_Q = (const float*)d_in[2];
    const float* W_K = (const float*)d_in[3];
    const float* b_K = (const float*)d_in[4];
    const float* W_V = (const float*)d_in[5];
    const float* b_V = (const float*)d_in[6];
    const int*   len = (const int*)d_in[7];
    float* out = (float*)d_out;

    // ws layout (bf16): Wbf[3072*1024] | Xbf[NB*20*1024] | Yqkv[NB*20*3072]
    // bytes needed: 6291456 + NB*163840
    int NB = 2048;
    while (NB > 32 && 6291456ull + (unsigned long long)NB * 163840ull > (unsigned long long)ws_size)
        NB >>= 1;
    if (6291456ull + (unsigned long long)NB * 163840ull > (unsigned long long)ws_size)
        return;  // ws too small even for NB=32: leave output zeroed (diagnostic signature)

    u16* Wbf = (u16*)d_ws;
    u16* Xbf = Wbf + 3145728;
    u16* Yq  = Xbf + (size_t)NB * 20480;

    cvt_bf16<<<512, 256, 0, stream>>>(W_Q, Wbf,           131072);
    cvt_bf16<<<512, 256, 0, stream>>>(W_K, Wbf + 1048576, 131072);
    cvt_bf16<<<512, 256, 0, stream>>>(W_V, Wbf + 2097152, 131072);

    const int nsl = 2048 / NB;
    for (int sI = 0; sI < nsl; ++sI) {
        int bBase = sI * NB;
        cvt_bf16<<<NB * 10, 256, 0, stream>>>(Q + (size_t)bBase * 20480, Xbf, NB * 2560);
        dim3 g(24, (NB * 20) / 128);
        gemm_qkv<<<g, 256, 0, stream>>>(Xbf, Wbf, b_Q, b_K, b_V, Yq);
        attn_dec<<<NB * 4, 256, 0, stream>>>(Yq, len + bBase, out + (size_t)bBase * 20480);
    }
}

// Round 3
// 634.727 us; speedup vs baseline: 1.4129x; 1.3666x over previous
//
#include <hip/hip_runtime.h>

typedef unsigned short u16;
typedef __attribute__((ext_vector_type(8))) __bf16 bf16x8;
typedef __attribute__((ext_vector_type(4))) float f32x4;
typedef __attribute__((ext_vector_type(16))) float f32x16;

__device__ __forceinline__ u16 f2bf(float x) {
    union { float f; unsigned int u; } v; v.f = x;
    unsigned int r = v.u + 0x7fffu + ((v.u >> 16) & 1u);
    return (u16)(r >> 16);
}

// direct global->LDS async copy, 16B per lane. LDS dest must be wave-uniform;
// HW writes base + lane*16.
typedef const __attribute__((address_space(1))) void* gas_ptr;
typedef __attribute__((address_space(3))) void* las_ptr;
#define GLOAD_LDS16(g, l) __builtin_amdgcn_global_load_lds((gas_ptr)(const void*)(g), (las_ptr)(void*)(l), 16, 0, 0)

// ---------------- fp32 -> bf16 conversion (8 elems/thread) ----------------
__global__ void cvt_bf16(const float* __restrict__ src, u16* __restrict__ dst, int n8) {
    int i = blockIdx.x * blockDim.x + threadIdx.x;
    if (i >= n8) return;
    const float4* s = (const float4*)src + (size_t)i * 2;
    float4 a = s[0], b = s[1];
    union { u16 u[8]; uint4 v; } o;
    o.u[0] = f2bf(a.x); o.u[1] = f2bf(a.y); o.u[2] = f2bf(a.z); o.u[3] = f2bf(a.w);
    o.u[4] = f2bf(b.x); o.u[5] = f2bf(b.y); o.u[6] = f2bf(b.z); o.u[7] = f2bf(b.w);
    *((uint4*)dst + i) = o.v;
}

// ---------------- QKV projection GEMM: Y[M][3072] = X[M][1024] @ Wcat^T + bias --------
// 256x256 tile, BK=64, 8 waves (2M x 4N), per-wave 128x64 output (acc[8][4] of f32x4).
// 8-phase-style schedule (m201 port): 4 phases per K-tile of {ds_read subtile |
// prefetch-issue} -> s_barrier -> setprio(1) 16xMFMA setprio(0) -> s_barrier.
// Next tile's 8 global_load_lds are issued in phases 1-2; the only vmcnt(0) drain is
// at the K-tile boundary, ~3 phases after issue (HBM latency hidden under MFMA).
// LDS tiles [256 rows][64 k] bf16 (128B rows) with XOR swizzle chunk ^= row&7 to break
// the 16-way ds_read_b128 bank conflict; global source is pre-inverse-swizzled so the
// linear global_load_lds write lands data at swizzled slots (both-sides rule, m231).
__global__ __launch_bounds__(512, 2) void gemm_qkv(
    const u16* __restrict__ X, const u16* __restrict__ W,
    const float* __restrict__ bQ, const float* __restrict__ bK,
    const float* __restrict__ bV, u16* __restrict__ Y)
{
    __shared__ __align__(16) u16 AB[2][2][16384];   // [buf][A,B][256*64] = 128 KiB
    const int tid = threadIdx.x;
    const int w = tid >> 6, lane = tid & 63;
    const int wave_m = w >> 2, wave_n = w & 3;
    const int l15 = lane & 15, l4 = lane >> 4, l7 = lane & 7;

    // bijective XCD swizzle (m204 variant; works for any nwg)
    const int nwg = gridDim.x;
    const int bid = blockIdx.x;
    const int q = nwg >> 3, r = nwg & 7;
    const int xcd = bid & 7, idx = bid >> 3;
    const int swz = (xcd < r ? xcd * (q + 1) : r * (q + 1) + (xcd - r) * q) + idx;
    const int bx = swz % 12, by = swz / 12;
    const size_t mBase = (size_t)by << 8;
    const int nBase = bx << 8;

    // staging source: lane covers 8 rows x 8 chunks per 1KB issue; logical k-chunk is
    // inverse-swizzled (lc ^ lr) so linear LDS writes produce swizzled content.
    const int lr = lane >> 3, lc = lane & 7, lcs = lc ^ lr;
    const u16* gA = X + (mBase + (size_t)(w * 32 + lr)) * 1024 + lcs * 8;
    const u16* gB = W + ((size_t)(nBase + w * 32 + lr)) * 1024 + lcs * 8;
    const int stOff = (w * 32) * 64;   // u16 offset of this wave's staging region

    f32x4 acc[8][4];
#pragma unroll
    for (int mi = 0; mi < 8; ++mi)
#pragma unroll
        for (int ni = 0; ni < 4; ++ni)
#pragma unroll
            for (int rr = 0; rr < 4; ++rr) acc[mi][ni][rr] = 0.f;

    // prologue: stage tile 0 into buf 0 (8 issues/wave), drain, barrier
#pragma unroll
    for (int j = 0; j < 4; ++j) {
        GLOAD_LDS16(gA + j * 8192, &AB[0][0][stOff + j * 512]);
        GLOAD_LDS16(gB + j * 8192, &AB[0][1][stOff + j * 512]);
    }
    asm volatile("s_waitcnt vmcnt(0)" ::: "memory");
    __builtin_amdgcn_s_barrier();
    __builtin_amdgcn_sched_barrier(0);

    const int aR = wave_m * 128 + l15;   // + mi*16
    const int bR = wave_n * 64 + l15;    // + ni*16
    const int ck0 = (l4 ^ l7) * 8;             // phys chunk byte/2 offset, ks=0
    const int ck1 = ((4 | l4) ^ l7) * 8;       // ks=1

    for (int t = 0; t < 16; ++t) {
        u16* curA = (t & 1) ? &AB[1][0][0] : &AB[0][0][0];
        u16* curB = (t & 1) ? &AB[1][1][0] : &AB[0][1][0];
        u16* stA  = (t & 1) ? &AB[0][0][stOff] : &AB[1][0][stOff];
        u16* stB  = (t & 1) ? &AB[0][1][stOff] : &AB[1][1][stOff];
        const int kNxt = (t + 1) * 64;
        const bool pf = (t < 15);

        bf16x8 a[4], b[4];
        // ---------- phase 1: mi 0-3, ks=0 ----------
#pragma unroll
        for (int ni = 0; ni < 4; ++ni)
            b[ni] = *(const bf16x8*)&curB[(bR + ni * 16) * 64 + ck0];
#pragma unroll
        for (int mi = 0; mi < 4; ++mi)
            a[mi] = *(const bf16x8*)&curA[(aR + mi * 16) * 64 + ck0];
        if (pf) {
            GLOAD_LDS16(gA + kNxt,        stA);
            GLOAD_LDS16(gA + kNxt + 8192, stA + 512);
            GLOAD_LDS16(gB + kNxt,        stB);
            GLOAD_LDS16(gB + kNxt + 8192, stB + 512);
        }
        __builtin_amdgcn_s_barrier();
        __builtin_amdgcn_s_setprio(1);
#pragma unroll
        for (int mi = 0; mi < 4; ++mi)
#pragma unroll
            for (int ni = 0; ni < 4; ++ni)
                acc[mi][ni] = __builtin_amdgcn_mfma_f32_16x16x32_bf16(a[mi], b[ni], acc[mi][ni], 0, 0, 0);
        __builtin_amdgcn_s_setprio(0);
        __builtin_amdgcn_s_barrier();

        // ---------- phase 2: mi 4-7, ks=0 (B reused) ----------
#pragma unroll
        for (int mi = 0; mi < 4; ++mi)
            a[mi] = *(const bf16x8*)&curA[(aR + (mi + 4) * 16) * 64 + ck0];
        if (pf) {
            GLOAD_LDS16(gA + kNxt + 16384, stA + 1024);
            GLOAD_LDS16(gA + kNxt + 24576, stA + 1536);
            GLOAD_LDS16(gB + kNxt + 16384, stB + 1024);
            GLOAD_LDS16(gB + kNxt + 24576, stB + 1536);
        }
        __builtin_amdgcn_s_barrier();
        __builtin_amdgcn_s_setprio(1);
#pragma unroll
        for (int mi = 0; mi < 4; ++mi)
#pragma unroll
            for (int ni = 0; ni < 4; ++ni)
                acc[mi + 4][ni] = __builtin_amdgcn_mfma_f32_16x16x32_bf16(a[mi], b[ni], acc[mi + 4][ni], 0, 0, 0);
        __builtin_amdgcn_s_setprio(0);
        __builtin_amdgcn_s_barrier();

        // ---------- phase 3: mi 0-3, ks=1 ----------
#pragma unroll
        for (int ni = 0; ni < 4; ++ni)
            b[ni] = *(const bf16x8*)&curB[(bR + ni * 16) * 64 + ck1];
#pragma unroll
        for (int mi = 0; mi < 4; ++mi)
            a[mi] = *(const bf16x8*)&curA[(aR + mi * 16) * 64 + ck1];
        __builtin_amdgcn_s_barrier();
        __builtin_amdgcn_s_setprio(1);
#pragma unroll
        for (int mi = 0; mi < 4; ++mi)
#pragma unroll
            for (int ni = 0; ni < 4; ++ni)
                acc[mi][ni] = __builtin_amdgcn_mfma_f32_16x16x32_bf16(a[mi], b[ni], acc[mi][ni], 0, 0, 0);
        __builtin_amdgcn_s_setprio(0);
        __builtin_amdgcn_s_barrier();

        // ---------- phase 4: mi 4-7, ks=1; tile-boundary drain ----------
#pragma unroll
        for (int mi = 0; mi < 4; ++mi)
            a[mi] = *(const bf16x8*)&curA[(aR + (mi + 4) * 16) * 64 + ck1];
        __builtin_amdgcn_s_barrier();
        __builtin_amdgcn_s_setprio(1);
#pragma unroll
        for (int mi = 0; mi < 4; ++mi)
#pragma unroll
            for (int ni = 0; ni < 4; ++ni)
                acc[mi + 4][ni] = __builtin_amdgcn_mfma_f32_16x16x32_bf16(a[mi], b[ni], acc[mi + 4][ni], 0, 0, 0);
        __builtin_amdgcn_s_setprio(0);
        asm volatile("s_waitcnt vmcnt(0)" ::: "memory");   // next tile's 8 loads landed (issued 3 phases ago)
        __builtin_amdgcn_s_barrier();
        __builtin_amdgcn_sched_barrier(0);
    }

    // epilogue: bias + bf16 store (C layout: col = lane&15, row = (lane>>4)*4 + r)
    const int third = nBase >> 10;
    const float* bias = (third == 0) ? bQ : ((third == 1) ? bK : bV);
    const int bcol = (nBase & 1023) + wave_n * 64 + l15;
    float bv[4];
#pragma unroll
    for (int ni = 0; ni < 4; ++ni) bv[ni] = bias[bcol + ni * 16];
#pragma unroll
    for (int mi = 0; mi < 8; ++mi) {
        size_t rb = mBase + wave_m * 128 + mi * 16 + l4 * 4;
#pragma unroll
        for (int ni = 0; ni < 4; ++ni) {
            int col = nBase + wave_n * 64 + ni * 16 + l15;
#pragma unroll
            for (int rr = 0; rr < 4; ++rr)
                Y[(rb + rr) * 3072 + col] = f2bf(acc[mi][ni][rr] + bv[ni]);
        }
    }
}

// ---------------- fused decay attention: one wave per (batch, head) ----------------
// scores = exp(q k^T / 8) masked by j<len; coef = scores/rowsum + Md; out = coef @ v.
__global__ __launch_bounds__(256) void attn_dec(
    const u16* __restrict__ Y, const int* __restrict__ lenp, float* __restrict__ out)
{
    __shared__ __align__(16) u16 coefLds[4][1024];   // [32][32] bf16 per wave
    __shared__ __align__(16) u16 vLds[4][1280];      // [20][64] bf16 per wave
    const int tid = threadIdx.x;
    const int w = tid >> 6, lane = tid & 63;
    const int u = blockIdx.x * 4 + w;
    const int b = u >> 4, h = u & 15;
    const int L = lenp[b];
    const int j32 = lane & 31, hw = lane >> 5;
    const int m19 = (j32 < 19) ? j32 : 19;

    const u16* qb = Y + (size_t)b * 61440 + h * 64;
    const u16* kb = qb + 1024;
    const u16* vb = qb + 2048;

    // QK^T : rows m = lane&31 (clamped), K over d=0..63 in 4 MFMAs
    f32x16 s;
    for (int r = 0; r < 16; ++r) s[r] = 0.f;
#pragma unroll
    for (int kc = 0; kc < 4; ++kc) {
        const int off = kc * 16 + hw * 8;
        bf16x8 aq = *(const bf16x8*)(qb + (size_t)m19 * 3072 + off);
        bf16x8 bk = *(const bf16x8*)(kb + (size_t)m19 * 3072 + off);
        s = __builtin_amdgcn_mfma_f32_32x32x16_bf16(aq, bk, s, 0, 0, 0);
    }

    // stage v[20][64] into LDS (16B chunks)
#pragma unroll
    for (int t = 0; t < 3; ++t) {
        int c = t * 64 + lane;
        if (c < 160) {
            uint4 d = *(const uint4*)(vb + (size_t)(c >> 3) * 3072 + (c & 7) * 8);
            *(uint4*)&vLds[w][c * 8] = d;
        }
    }

    // exp, mask, rowsum (32-lane butterfly), coef = attn + Md, store to LDS in A-layout
#pragma unroll
    for (int r = 0; r < 16; ++r) {
        int i = (r & 3) + ((r >> 2) << 3) + (hw << 2);
        float ev = (i < 20 && j32 < L) ? __expf(s[r] * 0.125f) : 0.f;
        float sum = ev;
#pragma unroll
        for (int o = 1; o < 32; o <<= 1) sum += __shfl_xor(sum, o, 32);
        float coef = ev / (sum + 1e-8f);
        if (i < 20 && j32 < 20) coef -= (float)((i > j32) ? (i - j32) : (j32 - i));
        if (i >= 20 || j32 >= 20) coef = 0.f;
        coefLds[w][i * 32 + j32] = f2bf(coef);
    }
    __syncthreads();

    // PV: D[i][d] = sum_j coef[i][j] v[j][d] ; N=64 as two 32-col tiles, K=32
    f32x16 o0, o1;
    for (int r = 0; r < 16; ++r) { o0[r] = 0.f; o1[r] = 0.f; }
#pragma unroll
    for (int kc = 0; kc < 2; ++kc) {
        bf16x8 ac = *(const bf16x8*)&coefLds[w][j32 * 32 + kc * 16 + hw * 8];
        bf16x8 bv0, bv1;
#pragma unroll
        for (int jj = 0; jj < 8; ++jj) {
            int j = kc * 16 + hw * 8 + jj;
            int jc = (j < 19) ? j : 19;     // coef=0 for j>=20; value irrelevant, stay in-bounds
            bv0[jj] = *(const __bf16*)&vLds[w][jc * 64 + j32];
            bv1[jj] = *(const __bf16*)&vLds[w][jc * 64 + 32 + j32];
        }
        o0 = __builtin_amdgcn_mfma_f32_32x32x16_bf16(ac, bv0, o0, 0, 0, 0);
        o1 = __builtin_amdgcn_mfma_f32_32x32x16_bf16(ac, bv1, o1, 0, 0, 0);
    }

#pragma unroll
    for (int r = 0; r < 16; ++r) {
        int i = (r & 3) + ((r >> 2) << 3) + (hw << 2);
        if (i < 20) {
            size_t ro = ((size_t)b * 20 + i) * 1024 + h * 64 + j32;
            out[ro] = o0[r];
            out[ro + 32] = o1[r];
        }
    }
}

// ---------------- driver ----------------
extern "C" void kernel_launch(void* const* d_in, const int* in_sizes, int n_in,
                              void* d_out, int out_size, void* d_ws, size_t ws_size,
                              hipStream_t stream) {
    const float* Q   = (const float*)d_in[0];
    const float* W_Q = (const float*)d_in[1];
    const float* b_Q = (const float*)d_in[2];
    const float* W_K = (const float*)d_in[3];
    const float* b_K = (const float*)d_in[4];
    const float* W_V = (const float*)d_in[5];
    const float* b_V = (const float*)d_in[6];
    const int*   len = (const int*)d_in[7];
    float* out = (float*)d_out;

    // ws layout (bf16): Wbf[3072*1024] | Xbf[NB*20*1024] | Yqkv[NB*20*3072]
    // bytes needed: 6291456 + NB*163840. NB must be a multiple of 64 so NB*20 % 256 == 0.
    int NB = 2048;
    while (NB > 64 && 6291456ull + (unsigned long long)NB * 163840ull > (unsigned long long)ws_size)
        NB >>= 1;
    if (6291456ull + (unsigned long long)NB * 163840ull > (unsigned long long)ws_size)
        return;  // ws too small: leave output zeroed (diagnostic signature)

    u16* Wbf = (u16*)d_ws;
    u16* Xbf = Wbf + 3145728;
    u16* Yq  = Xbf + (size_t)NB * 20480;

    cvt_bf16<<<512, 256, 0, stream>>>(W_Q, Wbf,           131072);
    cvt_bf16<<<512, 256, 0, stream>>>(W_K, Wbf + 1048576, 131072);
    cvt_bf16<<<512, 256, 0, stream>>>(W_V, Wbf + 2097152, 131072);

    const int nsl = 2048 / NB;
    for (int sI = 0; sI < nsl; ++sI) {
        int bBase = sI * NB;
        cvt_bf16<<<NB * 10, 256, 0, stream>>>(Q + (size_t)bBase * 20480, Xbf, NB * 2560);
        int nwg = 12 * ((NB * 20) >> 8);
        gemm_qkv<<<nwg, 512, 0, stream>>>(Xbf, Wbf, b_Q, b_K, b_V, Yq);
        attn_dec<<<NB * 4, 256, 0, stream>>>(Yq, len + bBase, out + (size_t)bBase * 20480);
    }
}